// Round 12
// baseline (31.615 us; speedup 1.0000x reference)
//
#include <hip/hip_runtime.h>

// Shapes fixed by reference setup_inputs(): (B=16, NI=11, T=65536), LST=64.
#define B_    16
#define NI    11
#define T_    65536
#define LST   64
#define SUPER 1024          // t-span per block (16 LST blocks)
#define RSTR  1040          // LDS row stride (floats), 16B-aligned, +16 pad

#define DPP_XOR1 0xB1       // quad_perm(1,0,3,2)  == xor lane^1
#define DPP_XOR2 0x4E       // quad_perm(2,3,0,1)  == xor lane^2

__device__ __forceinline__ float frcp(float x) { return __builtin_amdgcn_rcpf(x); }

template<int CTRL>
__device__ __forceinline__ float dppf(float x) {
    return __int_as_float(__builtin_amdgcn_update_dpp(
        0, __float_as_int(x), CTRL, 0xF, 0xF, true));
}
template<int CTRL>
__device__ __forceinline__ int dppi(int x) {
    return __builtin_amdgcn_update_dpp(0, x, CTRL, 0xF, 0xF, true);
}

__device__ __forceinline__ void ce_desc(float& a, float& b) {
    float mx = fmaxf(a, b);
    float mn = fminf(a, b);
    a = mx; b = mn;
}

// Exact d=11 sparsemax threshold for column c of the staged tile.
// Sort network (OETS-11) + one masked prefix pass (support is a prefix).
__device__ __forceinline__ float col_tau(float (*ldsz)[RSTR], int c) {
    float s[NI];
#pragma unroll
    for (int i = 0; i < NI; ++i) s[i] = ldsz[i][c];
#pragma unroll
    for (int p = 0; p < NI; ++p) {
#pragma unroll
        for (int k = (p & 1); k + 1 < NI; k += 2) ce_desc(s[k], s[k + 1]);
    }
    float cum = 0.0f, tsum = 0.0f;
    int   kz  = 0;
#pragma unroll
    for (int k = 1; k <= NI; ++k) {
        cum += s[k - 1];
        bool cond = fmaf((float)k, s[k - 1], 1.0f) > cum;   // 1 + k*s_k > cum_k
        kz   += cond ? 1 : 0;
        tsum += cond ? s[k - 1] : 0.0f;                     // cumsum[k_z-1]
    }
    return (tsum - 1.0f) * frcp((float)kz);
}

// Block = 11 waves (704 threads) covering 11 instruments x 1024 t.
// - wave w owns instrument w: 16 quad-tasks (one per LST block), ZERO
//   duplicate groups (the NI=11 vs power-of-2 waste is gone: 11264 waves
//   chip-wide vs 16384 before, -31%).
// - the contiguous row load (4x float4/lane = floats [16L,16L+16)) IS the
//   quad layout (quad j = lanes 4j..4j+3 holds LST block j), so the time
//   solve runs straight off the load registers, no LDS round trip.
// - instrument solve: 1024 columns over 704 threads (tid<320 takes a 2nd
//   column; waves 5-10 overlap their time solve with waves 0-4's 2nd pass).
__global__ __launch_bounds__(704) void fused_sparsemax_kernel(
        const float* __restrict__ in, float* __restrict__ out) {
    __shared__ float ldsz[NI][RSTR];    // staged tile, row-major [inst][t]
    __shared__ float ldsti[SUPER];      // tau_inst per t

    const int tid  = threadIdx.x;
    const int lane = tid & 63;
    const int w    = tid >> 6;          // wave id == instrument row
    const int b    = blockIdx.x >> 6;   // 64 supertiles per batch
    const int st   = blockIdx.x & 63;

    const size_t rbase = ((size_t)b * NI + w) * T_ + (size_t)st * SUPER
                       + (size_t)lane * 16;

    // ---- load row w: 4x dwordx4 per lane (wave covers 1024 floats) ----
    const float4* p4 = reinterpret_cast<const float4*>(in + rbase);
    float4 v0 = p4[0], v1 = p4[1], v2 = p4[2], v3 = p4[3];
    float y[16] = {v0.x, v0.y, v0.z, v0.w, v1.x, v1.y, v1.z, v1.w,
                   v2.x, v2.y, v2.z, v2.w, v3.x, v3.y, v3.z, v3.w};

    // stage for the column solve (4x ds_write_b128, conflict-free)
    float4* wp = reinterpret_cast<float4*>(&ldsz[w][lane * 16]);
    wp[0] = v0; wp[1] = v1; wp[2] = v2; wp[3] = v3;
    __syncthreads();

    // ---- instrument tau: thread per column (320 threads take 2) ----
    ldsti[tid] = col_tau(ldsz, tid);
    if (tid < SUPER - 704) {                        // tid < 320: waves 0-4
        ldsti[tid + 704] = col_tau(ldsz, tid + 704);
    }

    // ---- time tau: quad j = LST block j of row w, 16 elems/lane ----
    // warm start: tau0 = max(M1-1, (sum of 4 lane-maxes - 1)/4) <= tau*
    float lm = y[0];
#pragma unroll
    for (int r = 1; r < 16; ++r) lm = fmaxf(lm, y[r]);
    float M1 = fmaxf(lm, dppf<DPP_XOR1>(lm));
    M1 = fmaxf(M1, dppf<DPP_XOR2>(M1));
    float S4 = lm + dppf<DPP_XOR1>(lm);
    S4 += dppf<DPP_XOR2>(S4);
    float tau  = fmaxf(M1 - 1.0f, (S4 - 1.0f) * 0.25f);
    int   prev = 0;

#pragma unroll
    for (int it = 0; it < 3; ++it) {                // fixed, branch-free
        float ss = 0.0f;
        int   cc = 0;
#pragma unroll
        for (int r = 0; r < 16; ++r) {
            bool a = y[r] > tau;
            ss += a ? y[r] : 0.0f;
            cc += a ? 1 : 0;
        }
        ss += dppf<DPP_XOR1>(ss);
        ss += dppf<DPP_XOR2>(ss);
        cc += dppi<DPP_XOR1>(cc);
        cc += dppi<DPP_XOR2>(cc);
        tau  = (ss - 1.0f) * frcp((float)cc);
        prev = cc;
    }
    for (int it = 0; it < LST; ++it) {              // exact tail
        float ss = 0.0f;
        int   cc = 0;
#pragma unroll
        for (int r = 0; r < 16; ++r) {
            bool a = y[r] > tau;
            ss += a ? y[r] : 0.0f;
            cc += a ? 1 : 0;
        }
        cc += dppi<DPP_XOR1>(cc);
        cc += dppi<DPP_XOR2>(cc);
        if (!__any(cc != prev)) break;              // stable set -> exact KKT
        ss += dppf<DPP_XOR1>(ss);
        ss += dppf<DPP_XOR2>(ss);
        prev = cc;
        tau  = (ss - 1.0f) * frcp((float)cc);
    }

    __syncthreads();                                // ldsti complete

    // ---- epilogue: out = relu(y - tau_time) * relu(y - tau_inst) ----
    float ti[16];                                   // 4x ds_read_b128
#pragma unroll
    for (int r = 0; r < 16; ++r) ti[r] = ldsti[lane * 16 + r];

    float4* po4 = reinterpret_cast<float4*>(out + rbase);
#pragma unroll
    for (int v = 0; v < 4; ++v) {
        float4 o;
        o.x = fmaxf(y[4*v+0] - tau, 0.0f) * fmaxf(y[4*v+0] - ti[4*v+0], 0.0f);
        o.y = fmaxf(y[4*v+1] - tau, 0.0f) * fmaxf(y[4*v+1] - ti[4*v+1], 0.0f);
        o.z = fmaxf(y[4*v+2] - tau, 0.0f) * fmaxf(y[4*v+2] - ti[4*v+2], 0.0f);
        o.w = fmaxf(y[4*v+3] - tau, 0.0f) * fmaxf(y[4*v+3] - ti[4*v+3], 0.0f);
        po4[v] = o;
    }
}

extern "C" void kernel_launch(void* const* d_in, const int* in_sizes, int n_in,
                              void* d_out, int out_size, void* d_ws, size_t ws_size,
                              hipStream_t stream) {
    const float* in = (const float*)d_in[0];
    float* out = (float*)d_out;
    // 16 batches x 64 supertiles = 1024 blocks of 704 threads (11 waves)
    hipLaunchKernelGGL(fused_sparsemax_kernel, dim3(1024), dim3(704), 0, stream,
                       in, out);
}